// Round 4
// baseline (323.945 us; speedup 1.0000x reference)
//
#include <hip/hip_runtime.h>

// StockLSTM R17: two independent barrier domains per CU, register-safe.
//  R16 post-mortem: step = LDS-front (~940 cy: 16 waves x 5 ds_read_b128 =
//  80KB @85B/cy, nothing executable meanwhile) + VALU-back (~1140 cy trans).
//  Phase-skew inside one domain = null; the fix is overlapping one block's
//  back with the OTHER block's front:
//   - 512 threads (8 waves), each wave owns TWO 16-row gate tiles
//     (halves per-block LDS reads: B-frags shared across the wave's tiles)
//   - MT=8, grid=512 -> 2 blocks/CU @ 4 waves/SIMD (128-reg budget, NOT
//     R15's fatal 64). Dup-column trick via ADDRESSING only: lanes b8 and
//     b8+8 broadcast-read the same LDS word; A-frag rows differ per tile;
//     lane sel=(lane>>3)&1 keeps the tile matching its column half.
//  Per-thread math identical to R13 (2 cells, 20 trans). Register diet:
//  per-lane post-added bias (8 regs), zero-C MFMA starts, frag-lifetime
//  ordered MFMA blocks. Demand ~115 of 128.
//  SENTINEL: WRITE_SIZE must stay ~400 KB (spill signature = MB-scale).

#define TT   256
#define II   5
#define HH   64
#define OO   25
#define MT   8
#define NTHR 512
#define XP   520        // x chunk row stride (ushorts): 64*8 + 8 skew
#define HSZ  512        // h parity block: 64 k * 8 batch shorts
#define HF   65

typedef __attribute__((ext_vector_type(8))) short  short8;
typedef __attribute__((ext_vector_type(4))) float  floatx4;

#define MFMA(a, b, c) __builtin_amdgcn_mfma_f32_16x16x32_bf16(a, b, c, 0, 0, 0)

__device__ __forceinline__ float frcp(float x) { return __builtin_amdgcn_rcpf(x); }
__device__ __forceinline__ float fexp2(float x) { return __builtin_amdgcn_exp2f(x); }
__device__ __forceinline__ unsigned short bf16_rne(float f) {
    unsigned int u = __builtin_bit_cast(unsigned int, f);
    u += 0x7FFFu + ((u >> 16) & 1u);
    return (unsigned short)(u >> 16);
}
// gates arrive PRE-SCALED: g0,g1,g3 = -log2e*z ; g2 = +2log2e*z
__device__ __forceinline__ float cell_update(const floatx4& g, float& c) {
    const float gi = frcp(1.f + fexp2(g[0]));
    const float gf = frcp(1.f + fexp2(g[1]));
    const float gz = fmaf(-2.f, frcp(1.f + fexp2(g[2])), 1.f);
    const float go = frcp(1.f + fexp2(g[3]));
    c = fmaf(gf, c, gi * gz);
    const float tc = fmaf(-2.f, frcp(1.f + fexp2(c * 2.885390082f)), 1.f);
    return go * tc;
}

__global__ __attribute__((amdgpu_flat_work_group_size(512, 512),
                          amdgpu_waves_per_eu(4, 4)))
void lstm_mfma13(const float* __restrict__ x,
                 const float* __restrict__ Wih0, const float* __restrict__ Whh0,
                 const float* __restrict__ bih0, const float* __restrict__ bhh0,
                 const float* __restrict__ Wih1, const float* __restrict__ Whh1,
                 const float* __restrict__ bih1, const float* __restrict__ bhh1,
                 const float* __restrict__ Wfc,  const float* __restrict__ bfc,
                 float* __restrict__ out)
{
    __shared__ __align__(16) unsigned short xhi[MT * XP];     // 8.3 KB
    __shared__ __align__(16) unsigned short h1hi[2 * HSZ];    // 2 KB
    __shared__ __align__(16) unsigned short h2hi[2 * HSZ];    // 2 KB
    __shared__ __align__(16) float          h2f[MT * HF];     // 2.1 KB

    const int tid   = threadIdx.x;
    const int w     = tid >> 6;          // wave 0..7: owns tiles 2w, 2w+1
    const int lane  = tid & 63;
    const int b8    = lane & 7;          // batch col (8 real; cols 8-15 dup)
    const int q     = lane >> 4;         // k-octet / C row-quad
    const int sel   = (lane >> 3) & 1;   // which tile this lane's cells use
    const int jmine = 8 * w + 4 * sel + q;
    // h storage: [j>>3][b8][j&7] shorts
    const int hw_off = w * 64 + b8 * 8 + 4 * sel + q;
    const int ro8    = (q * 8 + b8) * 8; // B-frag read: lanes b8/b8+8 same addr

    // ---------------- weights (bf16), nonlinearity scale folded in ----------------
    short8 A1h[2][2];   // [tile][k-chunk] Whh0
    short8 A2h[2][4];   // [tile][k-chunk] 0,1: Wih1 (h1); 2,3: Whh1 (h2)
    short8 Axwh[2];     // [tile] Wih0: k<II valid, rest exact zero
    {
        const int rr = lane & 15;
        const float sc = ((rr & 3) == 2) ? 2.885390082f : -1.442695041f;
        #pragma unroll
        for (int s = 0; s < 2; ++s) {
            const int g = (rr & 3) * 64 + 4 * (2 * w + s) + (rr >> 2);
            #pragma unroll
            for (int c = 0; c < 2; ++c)
                #pragma unroll
                for (int jj = 0; jj < 8; ++jj)
                    A1h[s][c][jj] = (short)bf16_rne(sc * Whh0[g * HH + c * 32 + q * 8 + jj]);
            #pragma unroll
            for (int c = 0; c < 4; ++c)
                #pragma unroll
                for (int jj = 0; jj < 8; ++jj) {
                    const int k = c * 32 + q * 8 + jj;
                    float wv = (k < HH) ? Wih1[g * HH + k] : Whh1[g * HH + (k - HH)];
                    A2h[s][c][jj] = (short)bf16_rne(sc * wv);
                }
            #pragma unroll
            for (int jj = 0; jj < 8; ++jj) {
                const int k = q * 8 + jj;
                Axwh[s][jj] = (k < II) ? (short)bf16_rne(sc * Wih0[g * II + k]) : (short)0;
            }
        }
    }
    // per-lane bias for THIS lane's j (post-added to the selected gate vec)
    float bias1m[4], bias2m[4];
    #pragma unroll
    for (int r = 0; r < 4; ++r) {
        const int g = r * 64 + jmine;
        const float sc = (r == 2) ? 2.885390082f : -1.442695041f;
        bias1m[r] = sc * (bih0[g] + bhh0[g]);
        bias2m[r] = sc * (bih1[g] + bhh1[g]);
    }

    // ---------------- zero LDS ----------------
    for (int i = tid; i < MT * XP / 2; i += NTHR)
        ((unsigned int*)xhi)[i] = 0u;
    if (tid < HSZ) {
        ((unsigned int*)h1hi)[tid] = 0u;
        ((unsigned int*)h2hi)[tid] = 0u;
    }
    float c1 = 0.f, c2 = 0.f;
    __syncthreads();

    const int blockBase = blockIdx.x * MT;

    auto refill_x = [&](int t0) {
        const int rb = tid >> 6, dt = tid & 63;   // 8 rows x 64 t = 512 thr
        const float* src = x + ((size_t)(blockBase + rb) * TT + t0 + dt) * II;
        unsigned short* ph = xhi + rb * XP + dt * 8;
        #pragma unroll
        for (int ii = 0; ii < II; ++ii)
            ph[ii] = bf16_rne(src[ii]);
    };

    // ================= prologue: L1(0) =================
    refill_x(0);
    __syncthreads();
    {
        short8 Bxh = *(const short8*)(xhi + b8 * XP);       // dt = 0
        const floatx4 z4 = {0.f, 0.f, 0.f, 0.f};
        floatx4 a1t0 = MFMA(Axwh[0], Bxh, z4);
        floatx4 a1t1 = MFMA(Axwh[1], Bxh, z4);
        floatx4 g1;
        #pragma unroll
        for (int r = 0; r < 4; ++r)
            g1[r] = (sel ? a1t1[r] : a1t0[r]) + bias1m[r];
        const float h = cell_update(g1, c1);
        h1hi[0 * HSZ + hw_off] = bf16_rne(h);               // parity 0
    }
    __syncthreads();

    // x read pointer: STEP(i) reads dt=(i+1)&63; starts at dt=1.
    const unsigned short* xptr = xhi + b8 * XP + 8;

    // ================= merged main loop, unrolled by 2 =================
    // MFMAs grouped by B-fragment to cap fragment liveness (register diet).
#define STEP_BODY(WP, RP)                                                     \
    {                                                                         \
        short8 Bxh  = *(const short8*)(xptr);                                 \
        xptr += 8;                                                            \
        const floatx4 z4 = {0.f, 0.f, 0.f, 0.f};                              \
        floatx4 a1t0 = MFMA(Axwh[0], Bxh, z4);                                \
        floatx4 a1t1 = MFMA(Axwh[1], Bxh, z4);                                \
        short8 H1h0 = *(const short8*)(h1hi + (WP) * HSZ + ro8);              \
        floatx4 a2t0 = MFMA(A2h[0][0], H1h0, z4);                             \
        floatx4 a2t1 = MFMA(A2h[1][0], H1h0, z4);                             \
        a1t0 = MFMA(A1h[0][0], H1h0, a1t0);                                   \
        a1t1 = MFMA(A1h[1][0], H1h0, a1t1);                                   \
        short8 H1h1 = *(const short8*)(h1hi + (WP) * HSZ + 256 + ro8);        \
        a2t0 = MFMA(A2h[0][1], H1h1, a2t0);                                   \
        a2t1 = MFMA(A2h[1][1], H1h1, a2t1);                                   \
        a1t0 = MFMA(A1h[0][1], H1h1, a1t0);                                   \
        a1t1 = MFMA(A1h[1][1], H1h1, a1t1);                                   \
        short8 H2h0 = *(const short8*)(h2hi + (RP) * HSZ + ro8);              \
        a2t0 = MFMA(A2h[0][2], H2h0, a2t0);                                   \
        a2t1 = MFMA(A2h[1][2], H2h0, a2t1);                                   \
        short8 H2h1 = *(const short8*)(h2hi + (RP) * HSZ + 256 + ro8);        \
        a2t0 = MFMA(A2h[0][3], H2h1, a2t0);                                   \
        a2t1 = MFMA(A2h[1][3], H2h1, a2t1);                                   \
        floatx4 g2, g1;                                                       \
        _Pragma("unroll")                                                     \
        for (int r = 0; r < 4; ++r)                                           \
            g2[r] = (sel ? a2t1[r] : a2t0[r]) + bias2m[r];                    \
        _Pragma("unroll")                                                     \
        for (int r = 0; r < 4; ++r)                                           \
            g1[r] = (sel ? a1t1[r] : a1t0[r]) + bias1m[r];                    \
        {                                                                     \
            const float h = cell_update(g2, c2);                              \
            h2hi[(WP) * HSZ + hw_off] = bf16_rne(h);                          \
        }                                                                     \
        {                                                                     \
            const float h = cell_update(g1, c1);                              \
            h1hi[(RP) * HSZ + hw_off] = bf16_rne(h);                          \
        }                                                                     \
        __syncthreads();                                                      \
    }

    for (int i = 0; i < 254; i += 2) {
        STEP_BODY(0, 1)                      // interval i   (even)
        if (((i + 2) & 63) == 0) {           // refill before interval i+1
            refill_x(i + 2);
            xptr = xhi + b8 * XP;            //   next read is dt = 0
            __syncthreads();
        }
        STEP_BODY(1, 0)                      // interval i+1 (odd)
    }
    STEP_BODY(0, 1)                          // interval 254
#undef STEP_BODY

    // ================= epilogue: L2(255) =================
    {
        const floatx4 z4 = {0.f, 0.f, 0.f, 0.f};
        short8 H1h0 = *(const short8*)(h1hi + 1 * HSZ + ro8);
        floatx4 a2t0 = MFMA(A2h[0][0], H1h0, z4);
        floatx4 a2t1 = MFMA(A2h[1][0], H1h0, z4);
        short8 H1h1 = *(const short8*)(h1hi + 1 * HSZ + 256 + ro8);
        a2t0 = MFMA(A2h[0][1], H1h1, a2t0);
        a2t1 = MFMA(A2h[1][1], H1h1, a2t1);
        short8 H2h0 = *(const short8*)(h2hi + 0 * HSZ + ro8);
        a2t0 = MFMA(A2h[0][2], H2h0, a2t0);
        a2t1 = MFMA(A2h[1][2], H2h0, a2t1);
        short8 H2h1 = *(const short8*)(h2hi + 0 * HSZ + 256 + ro8);
        a2t0 = MFMA(A2h[0][3], H2h1, a2t0);
        a2t1 = MFMA(A2h[1][3], H2h1, a2t1);
        floatx4 g2;
        #pragma unroll
        for (int r = 0; r < 4; ++r)
            g2[r] = (sel ? a2t1[r] : a2t0[r]) + bias2m[r];
        const float h = cell_update(g2, c2);
        h2f[b8 * HF + jmine] = h;
    }
    __syncthreads();

    // ================= FC epilogue =================
    if (tid < MT * OO) {
        const int bb = tid / OO, o = tid - bb * OO;
        float acc = bfc[o];
        const float* wr = Wfc + o * HH;
        const float* hr = h2f + bb * HF;
        #pragma unroll
        for (int j = 0; j < HH; ++j) acc += wr[j] * hr[j];
        out[((size_t)blockIdx.x * MT + bb) * OO + o] = acc;
    }
}

extern "C" void kernel_launch(void* const* d_in, const int* in_sizes, int n_in,
                              void* d_out, int out_size, void* d_ws, size_t ws_size,
                              hipStream_t stream) {
    const float* x    = (const float*)d_in[0];
    const float* Wih0 = (const float*)d_in[1];
    const float* Whh0 = (const float*)d_in[2];
    const float* bih0 = (const float*)d_in[3];
    const float* bhh0 = (const float*)d_in[4];
    const float* Wih1 = (const float*)d_in[5];
    const float* Whh1 = (const float*)d_in[6];
    const float* bih1 = (const float*)d_in[7];
    const float* bhh1 = (const float*)d_in[8];
    const float* Wfc  = (const float*)d_in[9];
    const float* bfc  = (const float*)d_in[10];
    float* out = (float*)d_out;

    dim3 grid(4096 / MT), block(NTHR);
    lstm_mfma13<<<grid, block, 0, stream>>>(x, Wih0, Whh0, bih0, bhh0,
                                            Wih1, Whh1, bih1, bhh1,
                                            Wfc, bfc, out);
}

// Round 5
// 265.468 us; speedup vs baseline: 1.2203x; 1.2203x over previous
//
#include <hip/hip_runtime.h>

// StockLSTM R18: 8 waves x 2 tiles/wave, waves_per_eu(2,2) (256-reg budget).
//  R14/R15/R17 post-mortem: any >64-arch-VGPR variant under waves_per_eu(4,4)
//  spills (compiler splits the 128 budget 64 arch + 64 acc for MFMA kernels
//  and spills arch overflow; WRITE_SIZE 20-76 MB signatures). Fix: drop to
//  waves_per_eu(2,2) -> 256-reg budget; the 2-tile structure (~125 regs) fits.
//  Why 2 tiles/wave: R13's step = ~960cy LDS front (16 waves x 5 ds_read_b128,
//  all reading IDENTICAL h fragments - 16x redundant) + ~1000cy tail. 8 waves
//  reading the 5 B-frags once each and feeding TWO gate tiles halves the
//  front to ~480cy. MFMA count unchanged (14/wave x 8). VALU unchanged:
//  512 threads x 4 REAL cells (batch=16, both tiles fully used, no dup
//  columns, no selects). MT=16, grid=256, 1 block/CU.
//  SENTINEL: VGPR_Count must be >64 (~110-130) and WRITE_SIZE ~400 KB.

#define TT   256
#define II   5
#define HH   64
#define OO   25
#define MT   16
#define NTHR 512
#define XP   520        // x chunk row stride (ushorts): 64*8 + 8 skew
#define HSZ  1024       // h parity block: 64 k * 16 batch shorts
#define HF   65

typedef __attribute__((ext_vector_type(8))) short  short8;
typedef __attribute__((ext_vector_type(4))) float  floatx4;

#define MFMA(a, b, c) __builtin_amdgcn_mfma_f32_16x16x32_bf16(a, b, c, 0, 0, 0)

__device__ __forceinline__ float frcp(float x) { return __builtin_amdgcn_rcpf(x); }
__device__ __forceinline__ float fexp2(float x) { return __builtin_amdgcn_exp2f(x); }
__device__ __forceinline__ unsigned short bf16_rne(float f) {
    unsigned int u = __builtin_bit_cast(unsigned int, f);
    u += 0x7FFFu + ((u >> 16) & 1u);
    return (unsigned short)(u >> 16);
}
// gates arrive PRE-SCALED: g0,g1,g3 = -log2e*z ; g2 = +2log2e*z
__device__ __forceinline__ float cell_update(const floatx4& g, float& c) {
    const float gi = frcp(1.f + fexp2(g[0]));
    const float gf = frcp(1.f + fexp2(g[1]));
    const float gz = fmaf(-2.f, frcp(1.f + fexp2(g[2])), 1.f);
    const float go = frcp(1.f + fexp2(g[3]));
    c = fmaf(gf, c, gi * gz);
    const float tc = fmaf(-2.f, frcp(1.f + fexp2(c * 2.885390082f)), 1.f);
    return go * tc;
}

__global__ __attribute__((amdgpu_flat_work_group_size(512, 512),
                          amdgpu_waves_per_eu(2, 2)))
void lstm_mfma14(const float* __restrict__ x,
                 const float* __restrict__ Wih0, const float* __restrict__ Whh0,
                 const float* __restrict__ bih0, const float* __restrict__ bhh0,
                 const float* __restrict__ Wih1, const float* __restrict__ Whh1,
                 const float* __restrict__ bih1, const float* __restrict__ bhh1,
                 const float* __restrict__ Wfc,  const float* __restrict__ bfc,
                 float* __restrict__ out)
{
    __shared__ __align__(16) unsigned short xhi[MT * XP];     // 16.6 KB
    __shared__ __align__(16) unsigned short h1hi[2 * HSZ];    // 4 KB each
    __shared__ __align__(16) unsigned short h2hi[2 * HSZ];
    __shared__ __align__(16) float          h2f[MT * HF];

    const int tid   = threadIdx.x;
    const int w     = tid >> 6;          // wave 0..7: owns tiles 2w, 2w+1
    const int lane  = tid & 63;
    const int b     = lane & 15;         // batch col (16 real)
    const int q     = lane >> 4;         // k-octet / C row-quad
    const int j0    = 8 * w + q;         // hidden unit of tile 0
    const int j1    = 8 * w + 4 + q;     // hidden unit of tile 1
    // h storage: [j>>3][b][j&7] shorts -> j0: w*128+b*8+q ; j1: +4
    const int hw0   = w * 128 + b * 8 + q;
    const int hw1   = hw0 + 4;
    const int ro    = lane * 8;          // B-frag read offset: lane*16B

    // ---------------- weights (bf16), nonlinearity scale folded in ----------------
    short8 A1h[2][2];   // [tile][k-chunk] Whh0
    short8 A2h[2][4];   // [tile][k-chunk] 0,1: Wih1 (h1); 2,3: Whh1 (h2)
    short8 Axwh[2];     // [tile] Wih0: k<II valid, rest exact zero
    {
        const int rr = lane & 15;
        const float sc = ((rr & 3) == 2) ? 2.885390082f : -1.442695041f;
        #pragma unroll
        for (int s = 0; s < 2; ++s) {
            const int g = (rr & 3) * 64 + 8 * w + 4 * s + (rr >> 2);
            #pragma unroll
            for (int c = 0; c < 2; ++c)
                #pragma unroll
                for (int jj = 0; jj < 8; ++jj)
                    A1h[s][c][jj] = (short)bf16_rne(sc * Whh0[g * HH + c * 32 + q * 8 + jj]);
            #pragma unroll
            for (int c = 0; c < 4; ++c)
                #pragma unroll
                for (int jj = 0; jj < 8; ++jj) {
                    const int k = c * 32 + q * 8 + jj;
                    float wv = (k < HH) ? Wih1[g * HH + k] : Whh1[g * HH + (k - HH)];
                    A2h[s][c][jj] = (short)bf16_rne(sc * wv);
                }
            #pragma unroll
            for (int jj = 0; jj < 8; ++jj) {
                const int k = q * 8 + jj;
                Axwh[s][jj] = (k < II) ? (short)bf16_rne(sc * Wih0[g * II + k]) : (short)0;
            }
        }
    }
    // bias vectors as MFMA C-operands: [tile] -> lane's 4 gate rows of j(s)
    floatx4 bias1v[2], bias2v[2];
    #pragma unroll
    for (int s = 0; s < 2; ++s) {
        const int jj = 8 * w + 4 * s + q;
        #pragma unroll
        for (int r = 0; r < 4; ++r) {
            const int g = r * 64 + jj;
            const float sc = (r == 2) ? 2.885390082f : -1.442695041f;
            bias1v[s][r] = sc * (bih0[g] + bhh0[g]);
            bias2v[s][r] = sc * (bih1[g] + bhh1[g]);
        }
    }

    // ---------------- zero LDS ----------------
    for (int i = tid; i < MT * XP / 2; i += NTHR)
        ((unsigned int*)xhi)[i] = 0u;
    for (int i = tid; i < HSZ; i += NTHR) {      // HSZ uints = 2*HSZ shorts
        ((unsigned int*)h1hi)[i] = 0u;
        ((unsigned int*)h2hi)[i] = 0u;
    }
    float c1a = 0.f, c1b = 0.f, c2a = 0.f, c2b = 0.f;
    __syncthreads();

    const int blockBase = blockIdx.x * MT;

    auto refill_x = [&](int t0) {
        const int rb = tid >> 6, dt = tid & 63;
        #pragma unroll
        for (int rr2 = rb; rr2 < MT; rr2 += 8) {
            const float* src = x + ((size_t)(blockBase + rr2) * TT + t0 + dt) * II;
            unsigned short* ph = xhi + rr2 * XP + dt * 8;
            #pragma unroll
            for (int ii = 0; ii < II; ++ii)
                ph[ii] = bf16_rne(src[ii]);
        }
    };

    // ================= prologue: L1(0) =================
    refill_x(0);
    __syncthreads();
    {
        short8 Bxh = *(const short8*)(xhi + b * XP);       // dt = 0
        floatx4 a1t0 = MFMA(Axwh[0], Bxh, bias1v[0]);
        floatx4 a1t1 = MFMA(Axwh[1], Bxh, bias1v[1]);
        {
            const float h = cell_update(a1t0, c1a);
            h1hi[0 * HSZ + hw0] = bf16_rne(h);             // parity 0
        }
        {
            const float h = cell_update(a1t1, c1b);
            h1hi[0 * HSZ + hw1] = bf16_rne(h);
        }
    }
    __syncthreads();

    // x read pointer: STEP(i) reads dt=(i+1)&63; starts at dt=1.
    const unsigned short* xptr = xhi + b * XP + 8;

    // ================= merged main loop, unrolled by 2 =================
    // Each wave reads the 5 shared B-fragments ONCE, feeds both its tiles.
#define STEP_BODY(WP, RP)                                                     \
    {                                                                         \
        short8 H1h0 = *(const short8*)(h1hi + (WP) * HSZ + ro);               \
        short8 H1h1 = *(const short8*)(h1hi + (WP) * HSZ + 512 + ro);         \
        short8 H2h0 = *(const short8*)(h2hi + (RP) * HSZ + ro);               \
        short8 H2h1 = *(const short8*)(h2hi + (RP) * HSZ + 512 + ro);         \
        short8 Bxh  = *(const short8*)(xptr);                                 \
        xptr += 8;                                                            \
        floatx4 a2t0 = MFMA(A2h[0][0], H1h0, bias2v[0]);                      \
        floatx4 a2t1 = MFMA(A2h[1][0], H1h0, bias2v[1]);                      \
        a2t0 = MFMA(A2h[0][1], H1h1, a2t0);                                   \
        a2t1 = MFMA(A2h[1][1], H1h1, a2t1);                                   \
        a2t0 = MFMA(A2h[0][2], H2h0, a2t0);                                   \
        a2t1 = MFMA(A2h[1][2], H2h0, a2t1);                                   \
        a2t0 = MFMA(A2h[0][3], H2h1, a2t0);                                   \
        a2t1 = MFMA(A2h[1][3], H2h1, a2t1);                                   \
        floatx4 a1t0 = MFMA(Axwh[0], Bxh, bias1v[0]);                         \
        floatx4 a1t1 = MFMA(Axwh[1], Bxh, bias1v[1]);                         \
        a1t0 = MFMA(A1h[0][0], H1h0, a1t0);                                   \
        a1t1 = MFMA(A1h[1][0], H1h0, a1t1);                                   \
        a1t0 = MFMA(A1h[0][1], H1h1, a1t0);                                   \
        a1t1 = MFMA(A1h[1][1], H1h1, a1t1);                                   \
        {                                                                     \
            const float h = cell_update(a2t0, c2a);                           \
            h2hi[(WP) * HSZ + hw0] = bf16_rne(h);                             \
        }                                                                     \
        {                                                                     \
            const float h = cell_update(a2t1, c2b);                           \
            h2hi[(WP) * HSZ + hw1] = bf16_rne(h);                             \
        }                                                                     \
        {                                                                     \
            const float h = cell_update(a1t0, c1a);                           \
            h1hi[(RP) * HSZ + hw0] = bf16_rne(h);                             \
        }                                                                     \
        {                                                                     \
            const float h = cell_update(a1t1, c1b);                           \
            h1hi[(RP) * HSZ + hw1] = bf16_rne(h);                             \
        }                                                                     \
        __syncthreads();                                                      \
    }

    for (int i = 0; i < 254; i += 2) {
        STEP_BODY(0, 1)                      // interval i   (even)
        if (((i + 2) & 63) == 0) {           // refill before interval i+1
            refill_x(i + 2);
            xptr = xhi + b * XP;             //   next read is dt = 0
            __syncthreads();
        }
        STEP_BODY(1, 0)                      // interval i+1 (odd)
    }
    STEP_BODY(0, 1)                          // interval 254
#undef STEP_BODY

    // ================= epilogue: L2(255) =================
    {
        short8 H1h0 = *(const short8*)(h1hi + 1 * HSZ + ro);
        short8 H1h1 = *(const short8*)(h1hi + 1 * HSZ + 512 + ro);
        short8 H2h0 = *(const short8*)(h2hi + 0 * HSZ + ro);
        short8 H2h1 = *(const short8*)(h2hi + 0 * HSZ + 512 + ro);
        floatx4 a2t0 = MFMA(A2h[0][0], H1h0, bias2v[0]);
        floatx4 a2t1 = MFMA(A2h[1][0], H1h0, bias2v[1]);
        a2t0 = MFMA(A2h[0][1], H1h1, a2t0);
        a2t1 = MFMA(A2h[1][1], H1h1, a2t1);
        a2t0 = MFMA(A2h[0][2], H2h0, a2t0);
        a2t1 = MFMA(A2h[1][2], H2h0, a2t1);
        a2t0 = MFMA(A2h[0][3], H2h1, a2t0);
        a2t1 = MFMA(A2h[1][3], H2h1, a2t1);
        {
            const float h = cell_update(a2t0, c2a);
            h2f[b * HF + j0] = h;
        }
        {
            const float h = cell_update(a2t1, c2b);
            h2f[b * HF + j1] = h;
        }
    }
    __syncthreads();

    // ================= FC epilogue =================
    if (tid < MT * OO) {
        const int bb = tid / OO, o = tid - bb * OO;
        float acc = bfc[o];
        const float* wr = Wfc + o * HH;
        const float* hr = h2f + bb * HF;
        #pragma unroll
        for (int j = 0; j < HH; ++j) acc += wr[j] * hr[j];
        out[((size_t)blockIdx.x * MT + bb) * OO + o] = acc;
    }
}

extern "C" void kernel_launch(void* const* d_in, const int* in_sizes, int n_in,
                              void* d_out, int out_size, void* d_ws, size_t ws_size,
                              hipStream_t stream) {
    const float* x    = (const float*)d_in[0];
    const float* Wih0 = (const float*)d_in[1];
    const float* Whh0 = (const float*)d_in[2];
    const float* bih0 = (const float*)d_in[3];
    const float* bhh0 = (const float*)d_in[4];
    const float* Wih1 = (const float*)d_in[5];
    const float* Whh1 = (const float*)d_in[6];
    const float* bih1 = (const float*)d_in[7];
    const float* bhh1 = (const float*)d_in[8];
    const float* Wfc  = (const float*)d_in[9];
    const float* bfc  = (const float*)d_in[10];
    float* out = (float*)d_out;

    dim3 grid(4096 / MT), block(NTHR);
    lstm_mfma14<<<grid, block, 0, stream>>>(x, Wih0, Whh0, bih0, bhh0,
                                            Wih1, Whh1, bih1, bhh1,
                                            Wfc, bfc, out);
}